// Round 1
// baseline (8880.048 us; speedup 1.0000x reference)
//
#include <hip/hip_runtime.h>
#include <hip/hip_bf16.h>

#define B_ 2
#define N_ 16384
#define BN 32768
#define W_ 256
#define NF_ 256
#define E_ 524288
#define L_ 4
#define KSPLIT 16

__device__ __forceinline__ float geluf(float x) {
    return 0.5f * x * (1.0f + erff(x * 0.70710678118654752440f));
}

// ---------------- input projection: h = x @ p_w^T + p_b ----------------
__global__ __launch_bounds__(256) void k_in_proj(
    const float* __restrict__ x, const float* __restrict__ pw,
    const float* __restrict__ pb, float* __restrict__ h)
{
    int idx = blockIdx.x * 256 + threadIdx.x;
    int node = idx >> 8, w = idx & 255;
    float x0 = x[node*3+0], x1 = x[node*3+1], x2 = x[node*3+2];
    h[idx] = fmaf(x0, pw[w*3+0], fmaf(x1, pw[w*3+1], fmaf(x2, pw[w*3+2], pb[w])));
}

// ---------------- generic fp32 NT GEMM: C[m,n] (+)= sum_k A[m,k]*B[n,k] (+bias[n]) ----
template<bool ACCUM>
__global__ __launch_bounds__(256) void k_gemm_nt(
    const float* __restrict__ A, int lda, long sA,
    const float* __restrict__ Bm, int ldb, long sB,
    float* __restrict__ C, int ldc, long sC,
    const float* __restrict__ bias, int K)
{
    A  += (long)blockIdx.z * sA;
    Bm += (long)blockIdx.z * sB;
    C  += (long)blockIdx.z * sC;
    const int m0 = blockIdx.y * 64, n0 = blockIdx.x * 64;
    __shared__ float As[16][68], Bs[16][68];
    const int t = threadIdx.x;
    const int lrow = t >> 2, lq = (t & 3) * 4;
    const int ty = t >> 4, tx = t & 15;
    float acc[4][4] = {};
    for (int k0 = 0; k0 < K; k0 += 16) {
        float4 a4 = *(const float4*)(A  + (long)(m0+lrow)*lda + k0 + lq);
        float4 b4 = *(const float4*)(Bm + (long)(n0+lrow)*ldb + k0 + lq);
        As[lq+0][lrow]=a4.x; As[lq+1][lrow]=a4.y; As[lq+2][lrow]=a4.z; As[lq+3][lrow]=a4.w;
        Bs[lq+0][lrow]=b4.x; Bs[lq+1][lrow]=b4.y; Bs[lq+2][lrow]=b4.z; Bs[lq+3][lrow]=b4.w;
        __syncthreads();
        #pragma unroll
        for (int k = 0; k < 16; ++k) {
            float4 av = *(const float4*)&As[k][ty*4];
            float4 bv = *(const float4*)&Bs[k][tx*4];
            float a[4] = {av.x, av.y, av.z, av.w};
            float b[4] = {bv.x, bv.y, bv.z, bv.w};
            #pragma unroll
            for (int i = 0; i < 4; ++i)
                #pragma unroll
                for (int j = 0; j < 4; ++j)
                    acc[i][j] = fmaf(a[i], b[j], acc[i][j]);
        }
        __syncthreads();
    }
    #pragma unroll
    for (int i = 0; i < 4; ++i) {
        float* cp = C + (long)(m0+ty*4+i)*ldc + n0 + tx*4;
        float4 v = {acc[i][0], acc[i][1], acc[i][2], acc[i][3]};
        if (ACCUM) {
            float4 old = *(const float4*)cp;
            v.x += old.x; v.y += old.y; v.z += old.z; v.w += old.w;
        } else if (bias) {
            float4 bb = *(const float4*)(bias + n0 + tx*4);
            v.x += bb.x; v.y += bb.y; v.z += bb.z; v.w += bb.w;
        }
        *(float4*)cp = v;
    }
}

// ---------------- spectral fwd (TN, split-K): xftT[b,w,f] = sum_n U[b,n,f]*h[b,n,w] ----
__global__ __launch_bounds__(256) void k_spectral_fwd(
    const float* __restrict__ U, const float* __restrict__ h, float* __restrict__ xftT)
{
    const int f0 = blockIdx.x * 64, w0 = blockIdx.y * 64;
    const int b = blockIdx.z / KSPLIT, s = blockIdx.z % KSPLIT;
    const float* Ub = U + (long)b * N_ * NF_;
    const float* hb = h + (long)b * N_ * W_;
    __shared__ float Us[16][68], Hs[16][68];
    const int t = threadIdx.x;
    const int kq = t >> 6, c = t & 63;
    const int ty = t >> 4, tx = t & 15;
    float acc[4][4] = {};
    const int chunk = N_ / KSPLIT;
    const int kbase = s * chunk;
    for (int kk = 0; kk < chunk; kk += 16) {
        #pragma unroll
        for (int j = 0; j < 4; ++j) {
            int k = kq * 4 + j;
            Us[k][c] = Ub[(long)(kbase+kk+k)*NF_ + f0 + c];
            Hs[k][c] = hb[(long)(kbase+kk+k)*W_  + w0 + c];
        }
        __syncthreads();
        #pragma unroll
        for (int k = 0; k < 16; ++k) {
            float4 av = *(const float4*)&Us[k][ty*4];
            float4 bv = *(const float4*)&Hs[k][tx*4];
            float a[4] = {av.x, av.y, av.z, av.w};
            float b2[4] = {bv.x, bv.y, bv.z, bv.w};
            #pragma unroll
            for (int i = 0; i < 4; ++i)
                #pragma unroll
                for (int j = 0; j < 4; ++j)
                    acc[i][j] = fmaf(a[i], b2[j], acc[i][j]);
        }
        __syncthreads();
    }
    #pragma unroll
    for (int i = 0; i < 4; ++i)
        #pragma unroll
        for (int j = 0; j < 4; ++j)
            atomicAdd(&xftT[((long)b*W_ + (w0+tx*4+j))*NF_ + f0+ty*4+i], acc[i][j]);
}

// ---------------- fourier mul: oftT[b,o,f] = sum_i xftT[b,i,f]*fw[i,o,f] ----------------
__global__ __launch_bounds__(256) void k_fourier_mul(
    const float* __restrict__ fw, const float* __restrict__ xftT, float* __restrict__ oftT)
{
    const int o = blockIdx.x, s = blockIdx.y, f = threadIdx.x;
    const float* fwp = fw + (long)o*NF_ + f;
    float acc0 = 0.f, acc1 = 0.f;
    const int i0 = s * (W_/4);
    #pragma unroll 4
    for (int i = i0; i < i0 + W_/4; ++i) {
        float w = fwp[(long)i*W_*NF_];
        acc0 = fmaf(xftT[i*NF_ + f], w, acc0);
        acc1 = fmaf(xftT[W_*NF_ + i*NF_ + f], w, acc1);
    }
    atomicAdd(&oftT[o*NF_ + f], acc0);
    atomicAdd(&oftT[W_*NF_ + o*NF_ + f], acc1);
}

// ---------------- gelu + layernorm (wave per row of 256) ----------------
__global__ __launch_bounds__(256) void k_gelu_ln(
    float* __restrict__ xf, const float* __restrict__ wb,
    const float* __restrict__ lns, const float* __restrict__ lnb)
{
    const int node = blockIdx.x * 4 + (threadIdx.x >> 6);
    const int lane = threadIdx.x & 63;
    float4 v = *(const float4*)(xf + (long)node*W_ + lane*4);
    float4 bb = *(const float4*)(wb + lane*4);
    float e0 = geluf(v.x+bb.x), e1 = geluf(v.y+bb.y);
    float e2 = geluf(v.z+bb.z), e3 = geluf(v.w+bb.w);
    float s  = e0+e1+e2+e3;
    float s2 = e0*e0+e1*e1+e2*e2+e3*e3;
    #pragma unroll
    for (int o = 32; o; o >>= 1) { s += __shfl_xor(s, o); s2 += __shfl_xor(s2, o); }
    float mean = s * (1.0f/W_);
    float var  = s2 * (1.0f/W_) - mean*mean;
    float inv = rsqrtf(var + 1e-5f);
    float4 sc = *(const float4*)(lns + lane*4);
    float4 bi = *(const float4*)(lnb + lane*4);
    float4 outv;
    outv.x = (e0-mean)*inv*sc.x + bi.x;
    outv.y = (e1-mean)*inv*sc.y + bi.y;
    outv.z = (e2-mean)*inv*sc.z + bi.z;
    outv.w = (e3-mean)*inv*sc.w + bi.w;
    *(float4*)(xf + (long)node*W_ + lane*4) = outv;
}

// ---------------- edge gate MLP ----------------
__global__ __launch_bounds__(256) void k_edge_gate(
    const int* __restrict__ ei, const float* __restrict__ ewt,
    const float* __restrict__ lif,
    const float* __restrict__ eww, const float* __restrict__ ewb,
    const float* __restrict__ g1w, const float* __restrict__ g1b,
    const float* __restrict__ g2w, const float* __restrict__ g2b,
    float* __restrict__ g)
{
    int e = blockIdx.x * 256 + threadIdx.x;
    int src = ei[e], dst = ei[E_ + e];
    float wv = ewt[e];
    float gin[48];
    #pragma unroll
    for (int j = 0; j < 16; ++j) gin[j] = fmaf(wv, eww[j], ewb[j]);
    #pragma unroll
    for (int j = 0; j < 16; ++j) gin[16+j] = lif[dst*16+j];
    #pragma unroll
    for (int j = 0; j < 16; ++j) gin[32+j] = lif[src*16+j];
    float acc = g2b[0];
    #pragma unroll
    for (int c = 0; c < 3; ++c) {
        float t1 = g1b[c];
        #pragma unroll
        for (int j = 0; j < 48; ++j) t1 = fmaf(g1w[c*48+j], gin[j], t1);
        acc = fmaf(g2w[c], fmaxf(t1, 0.f), acc);
    }
    g[e] = 1.f / (1.f + __expf(-acc));
}

// ---------------- scatter-add: agg[dst] += xs[src]*g (wave per edge) ----------------
__global__ __launch_bounds__(256) void k_scatter(
    const int* __restrict__ ei, const float* __restrict__ g,
    const float* __restrict__ xs, float* __restrict__ agg)
{
    int e = blockIdx.x * 4 + (threadIdx.x >> 6);
    int lane = threadIdx.x & 63;
    int src = ei[e], dst = ei[E_ + e];
    float gv = g[e];
    float4 v = *(const float4*)(xs + (long)src*W_ + lane*4);
    float* ap = agg + (long)dst*W_ + lane*4;
    atomicAdd(ap+0, v.x*gv);
    atomicAdd(ap+1, v.y*gv);
    atomicAdd(ap+2, v.z*gv);
    atomicAdd(ap+3, v.w*gv);
}

// ---------------- L2 normalize rows ----------------
__global__ __launch_bounds__(256) void k_l2norm(
    const float* __restrict__ agg, float* __restrict__ xs)
{
    int node = blockIdx.x * 4 + (threadIdx.x >> 6);
    int lane = threadIdx.x & 63;
    float4 v = *(const float4*)(agg + (long)node*W_ + lane*4);
    float s = v.x*v.x + v.y*v.y + v.z*v.z + v.w*v.w;
    #pragma unroll
    for (int o = 32; o; o >>= 1) s += __shfl_xor(s, o);
    float inv = 1.f / fmaxf(sqrtf(s), 1e-12f);
    float4 r = {v.x*inv, v.y*inv, v.z*inv, v.w*inv};
    *(float4*)(xs + (long)node*W_ + lane*4) = r;
}

// ---------------- final q2: out[n] = sum_c relu(q1[n,c])*q2w[c] + q2b ----------------
__global__ __launch_bounds__(256) void k_q2(
    const float* __restrict__ q1o, const float* __restrict__ q2w,
    const float* __restrict__ q2b, float* __restrict__ out)
{
    int node = blockIdx.x * 4 + (threadIdx.x >> 6);
    int lane = threadIdx.x & 63;
    float a = fmaxf(q1o[(long)node*128 + lane], 0.f) * q2w[lane]
            + fmaxf(q1o[(long)node*128 + 64 + lane], 0.f) * q2w[64 + lane];
    #pragma unroll
    for (int o = 32; o; o >>= 1) a += __shfl_xor(a, o);
    if (lane == 0) out[node] = a + q2b[0];
}

extern "C" void kernel_launch(void* const* d_in, const int* in_sizes, int n_in,
                              void* d_out, int out_size, void* d_ws, size_t ws_size,
                              hipStream_t stream)
{
    const float* x      = (const float*)d_in[0];
    const float* U      = (const float*)d_in[1];
    const int*   ei     = (const int*)  d_in[2];
    const float* ewt    = (const float*)d_in[3];
    const float* lif    = (const float*)d_in[4];
    const float* p_w    = (const float*)d_in[5];
    const float* p_b    = (const float*)d_in[6];
    const float* four_w = (const float*)d_in[7];
    const float* w_w    = (const float*)d_in[8];
    const float* w_b    = (const float*)d_in[9];
    const float* ln_s   = (const float*)d_in[10];
    const float* ln_b   = (const float*)d_in[11];
    const float* lin_w  = (const float*)d_in[12];
    const float* lin_b  = (const float*)d_in[13];
    const float* ew_w   = (const float*)d_in[14];
    const float* ew_b   = (const float*)d_in[15];
    const float* g1_w   = (const float*)d_in[16];
    const float* g1_b   = (const float*)d_in[17];
    const float* g2_w   = (const float*)d_in[18];
    const float* g2_b   = (const float*)d_in[19];
    const float* proj_w = (const float*)d_in[20];
    const float* proj_b = (const float*)d_in[21];
    const float* q1_w   = (const float*)d_in[22];
    const float* q1_b   = (const float*)d_in[23];
    const float* q2_w   = (const float*)d_in[24];
    const float* q2_b   = (const float*)d_in[25];

    float* ws   = (float*)d_ws;
    float* h    = ws;
    float* xf   = ws + 1L*BN*W_;
    float* xs   = ws + 2L*BN*W_;
    float* agg  = ws + 3L*BN*W_;
    float* xftT = ws + 4L*BN*W_;
    float* oftT = xftT + (long)B_*W_*NF_;
    float* gbuf = oftT + (long)B_*W_*NF_;

    k_in_proj<<<BN, 256, 0, stream>>>(x, p_w, p_b, h);

    for (int l = 0; l < L_; ++l) {
        hipMemsetAsync(xftT, 0, (size_t)2*B_*W_*NF_*sizeof(float), stream);
        k_spectral_fwd<<<dim3(NF_/64, W_/64, B_*KSPLIT), 256, 0, stream>>>(U, h, xftT);
        k_fourier_mul<<<dim3(W_, 4), 256, 0, stream>>>(
            four_w + (long)l*W_*W_*NF_, xftT, oftT);
        // xf = U @ oftT^T (batched over b)
        k_gemm_nt<false><<<dim3(W_/64, N_/64, B_), 256, 0, stream>>>(
            U, NF_, (long)N_*NF_, oftT, NF_, (long)W_*NF_,
            xf, W_, (long)N_*W_, nullptr, NF_);
        // xf += h @ w_w[l]^T
        k_gemm_nt<true><<<dim3(W_/64, BN/64, 1), 256, 0, stream>>>(
            h, W_, 0, w_w + (long)l*W_*W_, W_, 0, xf, W_, 0, nullptr, W_);
        k_gelu_ln<<<BN/4, 256, 0, stream>>>(xf, w_b + l*W_, ln_s + l*W_, ln_b + l*W_);
        // xs = h @ lin_w[l]^T + lin_b
        k_gemm_nt<false><<<dim3(W_/64, BN/64, 1), 256, 0, stream>>>(
            h, W_, 0, lin_w + (long)l*W_*W_, W_, 0, xs, W_, 0, lin_b + l*W_, W_);
        k_edge_gate<<<E_/256, 256, 0, stream>>>(ei, ewt, lif,
            ew_w + l*16, ew_b + l*16, g1_w + l*144, g1_b + l*3,
            g2_w + l*3, g2_b + l, gbuf);
        hipMemsetAsync(agg, 0, (size_t)BN*W_*sizeof(float), stream);
        k_scatter<<<E_/4, 256, 0, stream>>>(ei, gbuf, xs, agg);
        k_l2norm<<<BN/4, 256, 0, stream>>>(agg, xs);
        // h = xf @ proj_w[:, :W]^T + proj_b ; h += xs @ proj_w[:, W:]^T
        k_gemm_nt<false><<<dim3(W_/64, BN/64, 1), 256, 0, stream>>>(
            xf, W_, 0, proj_w, 2*W_, 0, h, W_, 0, proj_b, W_);
        k_gemm_nt<true><<<dim3(W_/64, BN/64, 1), 256, 0, stream>>>(
            xs, W_, 0, proj_w + W_, 2*W_, 0, h, W_, 0, nullptr, W_);
    }
    // q1 = h @ q1_w^T + q1_b   (N=128), stored in xf
    k_gemm_nt<false><<<dim3(2, BN/64, 1), 256, 0, stream>>>(
        h, W_, 0, q1_w, W_, 0, xf, 128, 0, q1_b, W_);
    k_q2<<<BN/4, 256, 0, stream>>>(xf, q2_w, q2_b, (float*)d_out);
}

// Round 2
// 2272.312 us; speedup vs baseline: 3.9079x; 3.9079x over previous
//
#include <hip/hip_runtime.h>
#include <hip/hip_bf16.h>

#define B_ 2
#define N_ 16384
#define BN 32768
#define W_ 256
#define NF_ 256
#define E_ 524288
#define L_ 4
#define KSPLIT 16

__device__ __forceinline__ float geluf(float x) {
    return 0.5f * x * (1.0f + erff(x * 0.70710678118654752440f));
}

// ---------------- input projection: h = x @ p_w^T + p_b ----------------
__global__ __launch_bounds__(256) void k_in_proj(
    const float* __restrict__ x, const float* __restrict__ pw,
    const float* __restrict__ pb, float* __restrict__ h)
{
    int idx = blockIdx.x * 256 + threadIdx.x;
    int node = idx >> 8, w = idx & 255;
    float x0 = x[node*3+0], x1 = x[node*3+1], x2 = x[node*3+2];
    h[idx] = fmaf(x0, pw[w*3+0], fmaf(x1, pw[w*3+1], fmaf(x2, pw[w*3+2], pb[w])));
}

// ---------------- generic fp32 NT GEMM: C[m,n] (+)= sum_k A[m,k]*B[n,k] (+bias[n]) ----
template<bool ACCUM>
__global__ __launch_bounds__(256) void k_gemm_nt(
    const float* __restrict__ A, int lda, long sA,
    const float* __restrict__ Bm, int ldb, long sB,
    float* __restrict__ C, int ldc, long sC,
    const float* __restrict__ bias, int K)
{
    A  += (long)blockIdx.z * sA;
    Bm += (long)blockIdx.z * sB;
    C  += (long)blockIdx.z * sC;
    const int m0 = blockIdx.y * 64, n0 = blockIdx.x * 64;
    __shared__ float As[16][68], Bs[16][68];
    const int t = threadIdx.x;
    const int lrow = t >> 2, lq = (t & 3) * 4;
    const int ty = t >> 4, tx = t & 15;
    float acc[4][4] = {};
    for (int k0 = 0; k0 < K; k0 += 16) {
        float4 a4 = *(const float4*)(A  + (long)(m0+lrow)*lda + k0 + lq);
        float4 b4 = *(const float4*)(Bm + (long)(n0+lrow)*ldb + k0 + lq);
        As[lq+0][lrow]=a4.x; As[lq+1][lrow]=a4.y; As[lq+2][lrow]=a4.z; As[lq+3][lrow]=a4.w;
        Bs[lq+0][lrow]=b4.x; Bs[lq+1][lrow]=b4.y; Bs[lq+2][lrow]=b4.z; Bs[lq+3][lrow]=b4.w;
        __syncthreads();
        #pragma unroll
        for (int k = 0; k < 16; ++k) {
            float4 av = *(const float4*)&As[k][ty*4];
            float4 bv = *(const float4*)&Bs[k][tx*4];
            float a[4] = {av.x, av.y, av.z, av.w};
            float b[4] = {bv.x, bv.y, bv.z, bv.w};
            #pragma unroll
            for (int i = 0; i < 4; ++i)
                #pragma unroll
                for (int j = 0; j < 4; ++j)
                    acc[i][j] = fmaf(a[i], b[j], acc[i][j]);
        }
        __syncthreads();
    }
    #pragma unroll
    for (int i = 0; i < 4; ++i) {
        float* cp = C + (long)(m0+ty*4+i)*ldc + n0 + tx*4;
        float4 v = {acc[i][0], acc[i][1], acc[i][2], acc[i][3]};
        if (ACCUM) {
            float4 old = *(const float4*)cp;
            v.x += old.x; v.y += old.y; v.z += old.z; v.w += old.w;
        } else if (bias) {
            float4 bb = *(const float4*)(bias + n0 + tx*4);
            v.x += bb.x; v.y += bb.y; v.z += bb.z; v.w += bb.w;
        }
        *(float4*)cp = v;
    }
}

// ---------------- spectral fwd (TN, split-K): xftT[b,w,f] = sum_n U[b,n,f]*h[b,n,w] ----
__global__ __launch_bounds__(256) void k_spectral_fwd(
    const float* __restrict__ U, const float* __restrict__ h, float* __restrict__ xftT)
{
    const int f0 = blockIdx.x * 64, w0 = blockIdx.y * 64;
    const int b = blockIdx.z / KSPLIT, s = blockIdx.z % KSPLIT;
    const float* Ub = U + (long)b * N_ * NF_;
    const float* hb = h + (long)b * N_ * W_;
    __shared__ float Us[16][68], Hs[16][68];
    const int t = threadIdx.x;
    const int kq = t >> 6, c = t & 63;
    const int ty = t >> 4, tx = t & 15;
    float acc[4][4] = {};
    const int chunk = N_ / KSPLIT;
    const int kbase = s * chunk;
    for (int kk = 0; kk < chunk; kk += 16) {
        #pragma unroll
        for (int j = 0; j < 4; ++j) {
            int k = kq * 4 + j;
            Us[k][c] = Ub[(long)(kbase+kk+k)*NF_ + f0 + c];
            Hs[k][c] = hb[(long)(kbase+kk+k)*W_  + w0 + c];
        }
        __syncthreads();
        #pragma unroll
        for (int k = 0; k < 16; ++k) {
            float4 av = *(const float4*)&Us[k][ty*4];
            float4 bv = *(const float4*)&Hs[k][tx*4];
            float a[4] = {av.x, av.y, av.z, av.w};
            float b2[4] = {bv.x, bv.y, bv.z, bv.w};
            #pragma unroll
            for (int i = 0; i < 4; ++i)
                #pragma unroll
                for (int j = 0; j < 4; ++j)
                    acc[i][j] = fmaf(a[i], b2[j], acc[i][j]);
        }
        __syncthreads();
    }
    #pragma unroll
    for (int i = 0; i < 4; ++i)
        #pragma unroll
        for (int j = 0; j < 4; ++j)
            atomicAdd(&xftT[((long)b*W_ + (w0+tx*4+j))*NF_ + f0+ty*4+i], acc[i][j]);
}

// ---------------- fourier mul: oftT[b,o,f] = sum_i xftT[b,i,f]*fw[i,o,f] ----------------
__global__ __launch_bounds__(256) void k_fourier_mul(
    const float* __restrict__ fw, const float* __restrict__ xftT, float* __restrict__ oftT)
{
    const int o = blockIdx.x, s = blockIdx.y, f = threadIdx.x;
    const float* fwp = fw + (long)o*NF_ + f;
    float acc0 = 0.f, acc1 = 0.f;
    const int i0 = s * (W_/4);
    #pragma unroll 4
    for (int i = i0; i < i0 + W_/4; ++i) {
        float w = fwp[(long)i*W_*NF_];
        acc0 = fmaf(xftT[i*NF_ + f], w, acc0);
        acc1 = fmaf(xftT[W_*NF_ + i*NF_ + f], w, acc1);
    }
    atomicAdd(&oftT[o*NF_ + f], acc0);
    atomicAdd(&oftT[W_*NF_ + o*NF_ + f], acc1);
}

// ---------------- gelu + layernorm (wave per row of 256) ----------------
__global__ __launch_bounds__(256) void k_gelu_ln(
    float* __restrict__ xf, const float* __restrict__ wb,
    const float* __restrict__ lns, const float* __restrict__ lnb)
{
    const int node = blockIdx.x * 4 + (threadIdx.x >> 6);
    const int lane = threadIdx.x & 63;
    float4 v = *(const float4*)(xf + (long)node*W_ + lane*4);
    float4 bb = *(const float4*)(wb + lane*4);
    float e0 = geluf(v.x+bb.x), e1 = geluf(v.y+bb.y);
    float e2 = geluf(v.z+bb.z), e3 = geluf(v.w+bb.w);
    float s  = e0+e1+e2+e3;
    float s2 = e0*e0+e1*e1+e2*e2+e3*e3;
    #pragma unroll
    for (int o = 32; o; o >>= 1) { s += __shfl_xor(s, o); s2 += __shfl_xor(s2, o); }
    float mean = s * (1.0f/W_);
    float var  = s2 * (1.0f/W_) - mean*mean;
    float inv = rsqrtf(var + 1e-5f);
    float4 sc = *(const float4*)(lns + lane*4);
    float4 bi = *(const float4*)(lnb + lane*4);
    float4 outv;
    outv.x = (e0-mean)*inv*sc.x + bi.x;
    outv.y = (e1-mean)*inv*sc.y + bi.y;
    outv.z = (e2-mean)*inv*sc.z + bi.z;
    outv.w = (e3-mean)*inv*sc.w + bi.w;
    *(float4*)(xf + (long)node*W_ + lane*4) = outv;
}

// ================= CSR build (once per call; edge_index constant across layers) =====
__global__ __launch_bounds__(256) void k_hist(
    const int* __restrict__ ei, int* __restrict__ count)
{
    int e = blockIdx.x * 256 + threadIdx.x;
    atomicAdd(&count[ei[E_ + e]], 1);
}

// exclusive scan over 32768 counts, single workgroup
__global__ __launch_bounds__(256) void k_scan(
    const int* __restrict__ count, int* __restrict__ offsets)
{
    __shared__ int sums[256];
    const int t = threadIdx.x;
    const int base = t * 128;
    int s = 0;
    for (int i = 0; i < 128; ++i) s += count[base + i];
    sums[t] = s;
    __syncthreads();
    for (int off = 1; off < 256; off <<= 1) {
        int v = (t >= off) ? sums[t - off] : 0;
        __syncthreads();
        sums[t] += v;
        __syncthreads();
    }
    int run = (t == 0) ? 0 : sums[t - 1];
    for (int i = 0; i < 128; ++i) {
        offsets[base + i] = run;
        run += count[base + i];
    }
    if (t == 255) offsets[BN] = run;
}

__global__ __launch_bounds__(256) void k_place(
    const int* __restrict__ ei, const int* __restrict__ offsets,
    int* __restrict__ cursor, int* __restrict__ perm, int* __restrict__ srcp)
{
    int e = blockIdx.x * 256 + threadIdx.x;
    int dst = ei[E_ + e];
    int pos = offsets[dst] + atomicAdd(&cursor[dst], 1);
    perm[pos] = e;
    srcp[pos] = ei[e];
}

// ---------------- edge gate MLP (permuted order: output gp[pos]) ----------------
__global__ __launch_bounds__(256) void k_edge_gate(
    const int* __restrict__ perm, const int* __restrict__ srcp,
    const int* __restrict__ ei, const float* __restrict__ ewt,
    const float* __restrict__ lif,
    const float* __restrict__ eww, const float* __restrict__ ewb,
    const float* __restrict__ g1w, const float* __restrict__ g1b,
    const float* __restrict__ g2w, const float* __restrict__ g2b,
    float* __restrict__ gp)
{
    int pos = blockIdx.x * 256 + threadIdx.x;
    int e = perm[pos];
    int src = srcp[pos];
    int dst = ei[E_ + e];
    float wv = ewt[e];
    float gin[48];
    #pragma unroll
    for (int j = 0; j < 16; ++j) gin[j] = fmaf(wv, eww[j], ewb[j]);
    #pragma unroll
    for (int j = 0; j < 16; ++j) gin[16+j] = lif[dst*16+j];
    #pragma unroll
    for (int j = 0; j < 16; ++j) gin[32+j] = lif[src*16+j];
    float acc = g2b[0];
    #pragma unroll
    for (int c = 0; c < 3; ++c) {
        float t1 = g1b[c];
        #pragma unroll
        for (int j = 0; j < 48; ++j) t1 = fmaf(g1w[c*48+j], gin[j], t1);
        acc = fmaf(g2w[c], fmaxf(t1, 0.f), acc);
    }
    gp[pos] = 1.f / (1.f + __expf(-acc));
}

// ---------------- CSR aggregation + fused L2 normalize (wave per node) ----------------
__global__ __launch_bounds__(256) void k_agg_norm(
    const int* __restrict__ offsets, const int* __restrict__ srcp,
    const float* __restrict__ gp, const float* __restrict__ xs,
    float* __restrict__ out)
{
    const int node = blockIdx.x * 4 + (threadIdx.x >> 6);
    const int lane = threadIdx.x & 63;
    const int beg = offsets[node], end = offsets[node + 1];
    float4 acc = {0.f, 0.f, 0.f, 0.f};
    for (int p = beg; p < end; ++p) {
        const int src = srcp[p];
        const float gv = gp[p];
        float4 v = *(const float4*)(xs + (long)src * W_ + lane * 4);
        acc.x = fmaf(v.x, gv, acc.x);
        acc.y = fmaf(v.y, gv, acc.y);
        acc.z = fmaf(v.z, gv, acc.z);
        acc.w = fmaf(v.w, gv, acc.w);
    }
    float s = acc.x*acc.x + acc.y*acc.y + acc.z*acc.z + acc.w*acc.w;
    #pragma unroll
    for (int o = 32; o; o >>= 1) s += __shfl_xor(s, o);
    float inv = 1.f / fmaxf(sqrtf(s), 1e-12f);
    float4 r = {acc.x*inv, acc.y*inv, acc.z*inv, acc.w*inv};
    *(float4*)(out + (long)node * W_ + lane * 4) = r;
}

// ---------------- final q2: out[n] = sum_c relu(q1[n,c])*q2w[c] + q2b ----------------
__global__ __launch_bounds__(256) void k_q2(
    const float* __restrict__ q1o, const float* __restrict__ q2w,
    const float* __restrict__ q2b, float* __restrict__ out)
{
    int node = blockIdx.x * 4 + (threadIdx.x >> 6);
    int lane = threadIdx.x & 63;
    float a = fmaxf(q1o[(long)node*128 + lane], 0.f) * q2w[lane]
            + fmaxf(q1o[(long)node*128 + 64 + lane], 0.f) * q2w[64 + lane];
    #pragma unroll
    for (int o = 32; o; o >>= 1) a += __shfl_xor(a, o);
    if (lane == 0) out[node] = a + q2b[0];
}

extern "C" void kernel_launch(void* const* d_in, const int* in_sizes, int n_in,
                              void* d_out, int out_size, void* d_ws, size_t ws_size,
                              hipStream_t stream)
{
    const float* x      = (const float*)d_in[0];
    const float* U      = (const float*)d_in[1];
    const int*   ei     = (const int*)  d_in[2];
    const float* ewt    = (const float*)d_in[3];
    const float* lif    = (const float*)d_in[4];
    const float* p_w    = (const float*)d_in[5];
    const float* p_b    = (const float*)d_in[6];
    const float* four_w = (const float*)d_in[7];
    const float* w_w    = (const float*)d_in[8];
    const float* w_b    = (const float*)d_in[9];
    const float* ln_s   = (const float*)d_in[10];
    const float* ln_b   = (const float*)d_in[11];
    const float* lin_w  = (const float*)d_in[12];
    const float* lin_b  = (const float*)d_in[13];
    const float* ew_w   = (const float*)d_in[14];
    const float* ew_b   = (const float*)d_in[15];
    const float* g1_w   = (const float*)d_in[16];
    const float* g1_b   = (const float*)d_in[17];
    const float* g2_w   = (const float*)d_in[18];
    const float* g2_b   = (const float*)d_in[19];
    const float* proj_w = (const float*)d_in[20];
    const float* proj_b = (const float*)d_in[21];
    const float* q1_w   = (const float*)d_in[22];
    const float* q1_b   = (const float*)d_in[23];
    const float* q2_w   = (const float*)d_in[24];
    const float* q2_b   = (const float*)d_in[25];

    float* ws   = (float*)d_ws;
    float* h    = ws;
    float* xf   = ws + 1L*BN*W_;
    float* xs   = ws + 2L*BN*W_;
    float* xsn  = ws + 3L*BN*W_;       // normalized aggregation output
    float* xftT = ws + 4L*BN*W_;
    float* oftT = xftT + (long)B_*W_*NF_;
    float* gbuf = oftT + (long)B_*W_*NF_;
    int*   perm    = (int*)(gbuf + E_);
    int*   srcp    = perm + E_;
    int*   count   = srcp + E_;        // 32768
    int*   offsets = count + BN;       // 32769
    int*   cursor  = offsets + BN + 1; // 32768

    // ---- CSR build (edge_index is layer-invariant) ----
    hipMemsetAsync(count, 0, (size_t)BN * sizeof(int), stream);
    hipMemsetAsync(cursor, 0, (size_t)BN * sizeof(int), stream);
    k_hist<<<E_/256, 256, 0, stream>>>(ei, count);
    k_scan<<<1, 256, 0, stream>>>(count, offsets);
    k_place<<<E_/256, 256, 0, stream>>>(ei, offsets, cursor, perm, srcp);

    k_in_proj<<<BN, 256, 0, stream>>>(x, p_w, p_b, h);

    for (int l = 0; l < L_; ++l) {
        hipMemsetAsync(xftT, 0, (size_t)2*B_*W_*NF_*sizeof(float), stream);
        k_spectral_fwd<<<dim3(NF_/64, W_/64, B_*KSPLIT), 256, 0, stream>>>(U, h, xftT);
        k_fourier_mul<<<dim3(W_, 4), 256, 0, stream>>>(
            four_w + (long)l*W_*W_*NF_, xftT, oftT);
        // xf = U @ oftT^T (batched over b)
        k_gemm_nt<false><<<dim3(W_/64, N_/64, B_), 256, 0, stream>>>(
            U, NF_, (long)N_*NF_, oftT, NF_, (long)W_*NF_,
            xf, W_, (long)N_*W_, nullptr, NF_);
        // xf += h @ w_w[l]^T
        k_gemm_nt<true><<<dim3(W_/64, BN/64, 1), 256, 0, stream>>>(
            h, W_, 0, w_w + (long)l*W_*W_, W_, 0, xf, W_, 0, nullptr, W_);
        k_gelu_ln<<<BN/4, 256, 0, stream>>>(xf, w_b + l*W_, ln_s + l*W_, ln_b + l*W_);
        // xs = h @ lin_w[l]^T + lin_b
        k_gemm_nt<false><<<dim3(W_/64, BN/64, 1), 256, 0, stream>>>(
            h, W_, 0, lin_w + (long)l*W_*W_, W_, 0, xs, W_, 0, lin_b + l*W_, W_);
        k_edge_gate<<<E_/256, 256, 0, stream>>>(perm, srcp, ei, ewt, lif,
            ew_w + l*16, ew_b + l*16, g1_w + l*144, g1_b + l*3,
            g2_w + l*3, g2_b + l, gbuf);
        k_agg_norm<<<BN/4, 256, 0, stream>>>(offsets, srcp, gbuf, xs, xsn);
        // h = xf @ proj_w[:, :W]^T + proj_b ; h += xsn @ proj_w[:, W:]^T
        k_gemm_nt<false><<<dim3(W_/64, BN/64, 1), 256, 0, stream>>>(
            xf, W_, 0, proj_w, 2*W_, 0, h, W_, 0, proj_b, W_);
        k_gemm_nt<true><<<dim3(W_/64, BN/64, 1), 256, 0, stream>>>(
            xsn, W_, 0, proj_w + W_, 2*W_, 0, h, W_, 0, nullptr, W_);
    }
    // q1 = h @ q1_w^T + q1_b   (N=128), stored in xf
    k_gemm_nt<false><<<dim3(2, BN/64, 1), 256, 0, stream>>>(
        h, W_, 0, q1_w, W_, 0, xf, 128, 0, q1_b, W_);
    k_q2<<<BN/4, 256, 0, stream>>>(xf, q2_w, q2_b, (float*)d_out);
}

// Round 3
// 933.073 us; speedup vs baseline: 9.5170x; 2.4353x over previous
//
#include <hip/hip_runtime.h>
#include <hip/hip_bf16.h>

#define B_ 2
#define N_ 16384
#define BN 32768
#define W_ 256
#define NF_ 256
#define E_ 524288
#define L_ 4
#define KS_ 16   // split-K for spectral fwd

typedef __attribute__((ext_vector_type(8))) short bf16x8;
typedef __attribute__((ext_vector_type(4))) float f32x4;

__device__ __forceinline__ unsigned short f2b(float x) {
    __hip_bfloat16 h = __float2bfloat16(x);
    return *reinterpret_cast<unsigned short*>(&h);
}
__device__ __forceinline__ float b2f(unsigned short u) {
    union { unsigned int i; float f; } c; c.i = ((unsigned int)u) << 16; return c.f;
}
__device__ __forceinline__ float geluf(float x) {
    return 0.5f * x * (1.0f + erff(x * 0.70710678118654752440f));
}

// =============== bf16 MFMA NT GEMM: C[m,n] = sum_k A[m,k]B[n,k] (+ optional 2nd product, bias) ===============
// 128x128 tile, 4 waves of 64x64, BK=64, global_load_lds staging with XOR-swizzled LDS.
// z decomposition: zo=z/zdiv, zi=z%zdiv; A1 += zo*A1o+zi*A1i etc. OUTM: 0=f32 store, 1=bf16 store.
template<bool DUAL, int OUTM, bool BIAS>
__global__ __launch_bounds__(256) void k_mfma_nt(
    const unsigned short* __restrict__ A1, int lda1, long A1o, long A1i,
    const unsigned short* __restrict__ B1, int ldb1, long B1o, long B1i, int K1,
    const unsigned short* __restrict__ A2, int lda2, long A2o,
    const unsigned short* __restrict__ B2, int ldb2, long B2o, int K2,
    void* __restrict__ Cv, int ldc, long Co, long Ci,
    const float* __restrict__ bias, int zdiv)
{
    __shared__ unsigned short lds[16384];  // A: [0,8192) ushorts, B: [8192,16384)
    const int t = threadIdx.x;
    const int wid = t >> 6, lane = t & 63;
    const int wr = wid >> 1, wc = wid & 1;
    const int m0 = blockIdx.y * 128, n0 = blockIdx.x * 128;
    const int z = blockIdx.z;
    const int zo = z / zdiv, zi = z - zo * zdiv;
    A1 += zo * A1o + zi * A1i;
    B1 += zo * B1o + zi * B1i;
    if (DUAL) { A2 += zo * A2o; B2 += zo * B2o; }

    const int srow  = t >> 3;                 // staging row 0..31 per pass
    const int sgran = (t & 7) ^ (srow & 7);   // inverse-swizzled source granule
    const int rlo   = lane & 15;
    const int hi    = lane >> 4;

    f32x4 acc[4][4] = {};

    const int nph = DUAL ? 2 : 1;
    for (int ph = 0; ph < nph; ++ph) {
        const unsigned short* A  = (DUAL && ph) ? A2 : A1;
        const unsigned short* Bp = (DUAL && ph) ? B2 : B1;
        const int lda = (DUAL && ph) ? lda2 : lda1;
        const int ldb = (DUAL && ph) ? ldb2 : ldb1;
        const int K   = (DUAL && ph) ? K2 : K1;
        for (int k0 = 0; k0 < K; k0 += 64) {
            __syncthreads();
            #pragma unroll
            for (int j = 0; j < 4; ++j) {
                const unsigned short* ga = A + (long)(m0 + j*32 + srow) * lda + k0 + sgran*8;
                __builtin_amdgcn_global_load_lds(
                    (const __attribute__((address_space(1))) void*)ga,
                    (__attribute__((address_space(3))) void*)&lds[(j*4 + wid) * 512],
                    16, 0, 0);
            }
            #pragma unroll
            for (int j = 0; j < 4; ++j) {
                const unsigned short* gb = Bp + (long)(n0 + j*32 + srow) * ldb + k0 + sgran*8;
                __builtin_amdgcn_global_load_lds(
                    (const __attribute__((address_space(1))) void*)gb,
                    (__attribute__((address_space(3))) void*)&lds[8192 + (j*4 + wid) * 512],
                    16, 0, 0);
            }
            __syncthreads();
            #pragma unroll
            for (int kk = 0; kk < 2; ++kk) {
                const int g8 = (((kk*4 + hi) ^ (lane & 7)) << 3);
                bf16x8 a[4], b[4];
                #pragma unroll
                for (int fm = 0; fm < 4; ++fm)
                    a[fm] = *(const bf16x8*)&lds[(wr*64 + fm*16 + rlo)*64 + g8];
                #pragma unroll
                for (int fn = 0; fn < 4; ++fn)
                    b[fn] = *(const bf16x8*)&lds[8192 + (wc*64 + fn*16 + rlo)*64 + g8];
                #pragma unroll
                for (int fm = 0; fm < 4; ++fm)
                    #pragma unroll
                    for (int fn = 0; fn < 4; ++fn)
                        acc[fm][fn] = __builtin_amdgcn_mfma_f32_16x16x32_bf16(
                            a[fm], b[fn], acc[fm][fn], 0, 0, 0);
            }
        }
    }

    const int mb = m0 + wr*64, nb = n0 + wc*64;
    if (OUTM == 1) {
        unsigned short* C = (unsigned short*)Cv + zo * Co + zi * Ci;
        #pragma unroll
        for (int fn = 0; fn < 4; ++fn) {
            const int n = nb + fn*16 + rlo;
            const float bv = BIAS ? bias[n] : 0.f;
            #pragma unroll
            for (int fm = 0; fm < 4; ++fm)
                #pragma unroll
                for (int r = 0; r < 4; ++r) {
                    const int m = mb + fm*16 + hi*4 + r;
                    C[(long)m*ldc + n] = f2b(acc[fm][fn][r] + bv);
                }
        }
    } else {
        float* C = (float*)Cv + zo * Co + zi * Ci;
        #pragma unroll
        for (int fn = 0; fn < 4; ++fn) {
            const int n = nb + fn*16 + rlo;
            const float bv = BIAS ? bias[n] : 0.f;
            #pragma unroll
            for (int fm = 0; fm < 4; ++fm)
                #pragma unroll
                for (int r = 0; r < 4; ++r) {
                    const int m = mb + fm*16 + hi*4 + r;
                    C[(long)m*ldc + n] = acc[fm][fn][r] + bv;
                }
        }
    }
}

// =============== conversions / transposes ===============
__global__ __launch_bounds__(256) void k_cvt(const float* __restrict__ s, unsigned short* __restrict__ d) {
    long i = (long)(blockIdx.x * 256 + threadIdx.x) * 4;
    float4 v = *(const float4*)&s[i];
    ushort4 u = {f2b(v.x), f2b(v.y), f2b(v.z), f2b(v.w)};
    *(ushort4*)&d[i] = u;
}

// U fp32 [b][N_][NF_] -> UT bf16 [b][NF_][N_]  AND  U_bf bf16 [b][N_][NF_]
__global__ __launch_bounds__(256) void k_cvtT(
    const float* __restrict__ src, unsigned short* __restrict__ dT, unsigned short* __restrict__ dL)
{
    const int b = blockIdx.z;
    src += (long)b * N_ * NF_; dT += (long)b * N_ * NF_; dL += (long)b * N_ * NF_;
    const int r0 = blockIdx.y * 64, c0 = blockIdx.x * 64;
    __shared__ unsigned short tile[64][72];
    const int t = threadIdx.x, lr = t >> 4, lc4 = (t & 15) * 4;
    #pragma unroll
    for (int p = 0; p < 4; ++p) {
        int r = p*16 + lr;
        float4 v = *(const float4*)&src[(long)(r0+r)*NF_ + c0 + lc4];
        ushort4 u = {f2b(v.x), f2b(v.y), f2b(v.z), f2b(v.w)};
        *(ushort4*)&dL[(long)(r0+r)*NF_ + c0 + lc4] = u;
        tile[r][lc4+0]=u.x; tile[r][lc4+1]=u.y; tile[r][lc4+2]=u.z; tile[r][lc4+3]=u.w;
    }
    __syncthreads();
    #pragma unroll
    for (int p = 0; p < 4; ++p) {
        int c = p*16 + lr;
        ushort4 u = {tile[lc4+0][c], tile[lc4+1][c], tile[lc4+2][c], tile[lc4+3][c]};
        *(ushort4*)&dT[(long)(c0+c)*N_ + r0 + lc4] = u;
    }
}

// h bf16 [b][N_][W_] -> hT bf16 [b][W_][N_]
__global__ __launch_bounds__(256) void k_T_b2b(
    const unsigned short* __restrict__ src, unsigned short* __restrict__ dst)
{
    const int b = blockIdx.z;
    src += (long)b * N_ * W_; dst += (long)b * N_ * W_;
    const int r0 = blockIdx.y * 64, c0 = blockIdx.x * 64;
    __shared__ unsigned short tile[64][72];
    const int t = threadIdx.x, lr = t >> 4, lc4 = (t & 15) * 4;
    #pragma unroll
    for (int p = 0; p < 4; ++p) {
        int r = p*16 + lr;
        ushort4 v = *(const ushort4*)&src[(long)(r0+r)*W_ + c0 + lc4];
        tile[r][lc4+0]=v.x; tile[r][lc4+1]=v.y; tile[r][lc4+2]=v.z; tile[r][lc4+3]=v.w;
    }
    __syncthreads();
    #pragma unroll
    for (int p = 0; p < 4; ++p) {
        int c = p*16 + lr;
        ushort4 u = {tile[lc4+0][c], tile[lc4+1][c], tile[lc4+2][c], tile[lc4+3][c]};
        *(ushort4*)&dst[(long)(c0+c)*N_ + r0 + lc4] = u;
    }
}

// =============== small fused kernels ===============
__global__ __launch_bounds__(256) void k_in_proj(
    const float* __restrict__ x, const float* __restrict__ pw,
    const float* __restrict__ pb, unsigned short* __restrict__ h)
{
    int idx = blockIdx.x * 256 + threadIdx.x;
    int node = idx >> 8, w = idx & 255;
    float x0 = x[node*3+0], x1 = x[node*3+1], x2 = x[node*3+2];
    h[idx] = f2b(fmaf(x0, pw[w*3+0], fmaf(x1, pw[w*3+1], fmaf(x2, pw[w*3+2], pb[w]))));
}

// reduce split-K partials: xftT[b][i][f] = sum_s part[b*KS_+s][i][f]
__global__ __launch_bounds__(256) void k_reduce_ks(
    const float* __restrict__ part, float* __restrict__ outp)
{
    int idx = blockIdx.x * 256 + threadIdx.x;   // 0 .. 2*65536-1
    int b = idx >> 16, rem = idx & 65535;
    const float* p = part + (long)b * KS_ * 65536 + rem;
    float s = 0.f;
    #pragma unroll
    for (int k = 0; k < KS_; ++k) s += p[(long)k * 65536];
    outp[idx] = s;
}

// oftT[b][o][f] = sum_i xftT[b][i][f] * fw[i][o][f], bf16 out
__global__ __launch_bounds__(256) void k_fourier_mul(
    const float* __restrict__ fw, const float* __restrict__ xftT,
    unsigned short* __restrict__ oftT)
{
    const int o = blockIdx.x, f = threadIdx.x;
    const float* fwp = fw + (long)o * NF_ + f;
    float a0 = 0.f, a1 = 0.f;
    #pragma unroll 8
    for (int i = 0; i < W_; ++i) {
        float w = fwp[(long)i * W_ * NF_];
        a0 = fmaf(xftT[i*NF_ + f], w, a0);
        a1 = fmaf(xftT[65536 + i*NF_ + f], w, a1);
    }
    oftT[o*NF_ + f] = f2b(a0);
    oftT[65536 + o*NF_ + f] = f2b(a1);
}

__global__ __launch_bounds__(256) void k_gelu_ln(
    const float* __restrict__ xf, unsigned short* __restrict__ out,
    const float* __restrict__ wb, const float* __restrict__ lns, const float* __restrict__ lnb)
{
    const int node = blockIdx.x * 4 + (threadIdx.x >> 6);
    const int lane = threadIdx.x & 63;
    float4 v = *(const float4*)(xf + (long)node*W_ + lane*4);
    float4 bb = *(const float4*)(wb + lane*4);
    float e0 = geluf(v.x+bb.x), e1 = geluf(v.y+bb.y);
    float e2 = geluf(v.z+bb.z), e3 = geluf(v.w+bb.w);
    float s  = e0+e1+e2+e3;
    float s2 = e0*e0+e1*e1+e2*e2+e3*e3;
    #pragma unroll
    for (int o = 32; o; o >>= 1) { s += __shfl_xor(s, o); s2 += __shfl_xor(s2, o); }
    float mean = s * (1.0f/W_);
    float var  = s2 * (1.0f/W_) - mean*mean;
    float inv = rsqrtf(var + 1e-5f);
    float4 sc = *(const float4*)(lns + lane*4);
    float4 bi = *(const float4*)(lnb + lane*4);
    ushort4 o4;
    o4.x = f2b((e0-mean)*inv*sc.x + bi.x);
    o4.y = f2b((e1-mean)*inv*sc.y + bi.y);
    o4.z = f2b((e2-mean)*inv*sc.z + bi.z);
    o4.w = f2b((e3-mean)*inv*sc.w + bi.w);
    *(ushort4*)(out + (long)node*W_ + lane*4) = o4;
}

// =============== CSR build ===============
__global__ __launch_bounds__(256) void k_hist(const int* __restrict__ ei, int* __restrict__ count) {
    int e = blockIdx.x * 256 + threadIdx.x;
    atomicAdd(&count[ei[E_ + e]], 1);
}
__global__ __launch_bounds__(256) void k_scan(const int* __restrict__ count, int* __restrict__ offsets) {
    __shared__ int sums[256];
    const int t = threadIdx.x;
    const int base = t * 128;
    int s = 0;
    for (int i = 0; i < 128; ++i) s += count[base + i];
    sums[t] = s;
    __syncthreads();
    for (int off = 1; off < 256; off <<= 1) {
        int v = (t >= off) ? sums[t - off] : 0;
        __syncthreads();
        sums[t] += v;
        __syncthreads();
    }
    int run = (t == 0) ? 0 : sums[t - 1];
    for (int i = 0; i < 128; ++i) { offsets[base + i] = run; run += count[base + i]; }
    if (t == 255) offsets[BN] = run;
}
__global__ __launch_bounds__(256) void k_place(
    const int* __restrict__ ei, const int* __restrict__ offsets,
    int* __restrict__ cursor, int* __restrict__ perm, int* __restrict__ srcp)
{
    int e = blockIdx.x * 256 + threadIdx.x;
    int dst = ei[E_ + e];
    int pos = offsets[dst] + atomicAdd(&cursor[dst], 1);
    perm[pos] = e;
    srcp[pos] = ei[e];
}

// =============== edge gate MLP (permuted order) ===============
__global__ __launch_bounds__(256) void k_edge_gate(
    const int* __restrict__ perm, const int* __restrict__ srcp,
    const int* __restrict__ ei, const float* __restrict__ ewt,
    const float* __restrict__ lif,
    const float* __restrict__ eww, const float* __restrict__ ewb,
    const float* __restrict__ g1w, const float* __restrict__ g1b,
    const float* __restrict__ g2w, const float* __restrict__ g2b,
    float* __restrict__ gp)
{
    int pos = blockIdx.x * 256 + threadIdx.x;
    int e = perm[pos];
    int src = srcp[pos];
    int dst = ei[E_ + e];
    float wv = ewt[e];
    float gin[48];
    #pragma unroll
    for (int j = 0; j < 16; ++j) gin[j] = fmaf(wv, eww[j], ewb[j]);
    #pragma unroll
    for (int j = 0; j < 16; ++j) gin[16+j] = lif[dst*16+j];
    #pragma unroll
    for (int j = 0; j < 16; ++j) gin[32+j] = lif[src*16+j];
    float acc = g2b[0];
    #pragma unroll
    for (int c = 0; c < 3; ++c) {
        float t1 = g1b[c];
        #pragma unroll
        for (int j = 0; j < 48; ++j) t1 = fmaf(g1w[c*48+j], gin[j], t1);
        acc = fmaf(g2w[c], fmaxf(t1, 0.f), acc);
    }
    gp[pos] = 1.f / (1.f + __expf(-acc));
}

// =============== CSR aggregation + L2 normalize (wave/node, bf16 in/out) ===============
__global__ __launch_bounds__(256) void k_agg_norm(
    const int* __restrict__ offsets, const int* __restrict__ srcp,
    const float* __restrict__ gp, const unsigned short* __restrict__ xs,
    unsigned short* __restrict__ out)
{
    const int node = blockIdx.x * 4 + (threadIdx.x >> 6);
    const int lane = threadIdx.x & 63;
    const int beg = offsets[node], end = offsets[node + 1];
    float a0=0.f, a1=0.f, a2=0.f, a3=0.f;
    for (int p = beg; p < end; ++p) {
        const int src = srcp[p];
        const float gv = gp[p];
        ushort4 v = *(const ushort4*)&xs[(long)src * W_ + lane * 4];
        a0 = fmaf(b2f(v.x), gv, a0);
        a1 = fmaf(b2f(v.y), gv, a1);
        a2 = fmaf(b2f(v.z), gv, a2);
        a3 = fmaf(b2f(v.w), gv, a3);
    }
    float s = a0*a0 + a1*a1 + a2*a2 + a3*a3;
    #pragma unroll
    for (int o = 32; o; o >>= 1) s += __shfl_xor(s, o);
    float inv = 1.f / fmaxf(sqrtf(s), 1e-12f);
    ushort4 r = {f2b(a0*inv), f2b(a1*inv), f2b(a2*inv), f2b(a3*inv)};
    *(ushort4*)(out + (long)node * W_ + lane * 4) = r;
}

// =============== final q2 ===============
__global__ __launch_bounds__(256) void k_q2(
    const float* __restrict__ q1o, const float* __restrict__ q2w,
    const float* __restrict__ q2b, float* __restrict__ out)
{
    int node = blockIdx.x * 4 + (threadIdx.x >> 6);
    int lane = threadIdx.x & 63;
    float a = fmaxf(q1o[(long)node*128 + lane], 0.f) * q2w[lane]
            + fmaxf(q1o[(long)node*128 + 64 + lane], 0.f) * q2w[64 + lane];
    #pragma unroll
    for (int o = 32; o; o >>= 1) a += __shfl_xor(a, o);
    if (lane == 0) out[node] = a + q2b[0];
}

extern "C" void kernel_launch(void* const* d_in, const int* in_sizes, int n_in,
                              void* d_out, int out_size, void* d_ws, size_t ws_size,
                              hipStream_t stream)
{
    const float* x      = (const float*)d_in[0];
    const float* U      = (const float*)d_in[1];
    const int*   ei     = (const int*)  d_in[2];
    const float* ewt    = (const float*)d_in[3];
    const float* lif    = (const float*)d_in[4];
    const float* p_w    = (const float*)d_in[5];
    const float* p_b    = (const float*)d_in[6];
    const float* four_w = (const float*)d_in[7];
    const float* w_w    = (const float*)d_in[8];
    const float* w_b    = (const float*)d_in[9];
    const float* ln_s   = (const float*)d_in[10];
    const float* ln_b   = (const float*)d_in[11];
    const float* lin_w  = (const float*)d_in[12];
    const float* lin_b  = (const float*)d_in[13];
    const float* ew_w   = (const float*)d_in[14];
    const float* ew_b   = (const float*)d_in[15];
    const float* g1_w   = (const float*)d_in[16];
    const float* g1_b   = (const float*)d_in[17];
    const float* g2_w   = (const float*)d_in[18];
    const float* g2_b   = (const float*)d_in[19];
    const float* proj_w = (const float*)d_in[20];
    const float* proj_b = (const float*)d_in[21];
    const float* q1_w   = (const float*)d_in[22];
    const float* q1_b   = (const float*)d_in[23];
    const float* q2_w   = (const float*)d_in[24];
    const float* q2_b   = (const float*)d_in[25];

    char* wsb = (char*)d_ws;
    size_t off = 0;
    auto alloc = [&](size_t bytes) -> void* {
        void* p = wsb + off; off += (bytes + 255) & ~(size_t)255; return p;
    };
    float* xf        = (float*)alloc((size_t)BN * W_ * 4);        // fp32 GEMM out; reused as q1o
    float* xft_part  = (float*)alloc((size_t)B_ * KS_ * 65536 * 4);
    float* xftT      = (float*)alloc((size_t)B_ * 65536 * 4);
    float* gbuf      = (float*)alloc((size_t)E_ * 4);
    unsigned short* h_bf   = (unsigned short*)alloc((size_t)BN * W_ * 2);
    unsigned short* hT_bf  = (unsigned short*)alloc((size_t)BN * W_ * 2);
    unsigned short* U_bf   = (unsigned short*)alloc((size_t)BN * NF_ * 2);
    unsigned short* UT_bf  = (unsigned short*)alloc((size_t)BN * NF_ * 2);
    unsigned short* xf_bf  = (unsigned short*)alloc((size_t)BN * W_ * 2);
    unsigned short* xs_bf  = (unsigned short*)alloc((size_t)BN * W_ * 2);
    unsigned short* xsn_bf = (unsigned short*)alloc((size_t)BN * W_ * 2);
    unsigned short* oftT_bf= (unsigned short*)alloc((size_t)B_ * 65536 * 2);
    unsigned short* wwb    = (unsigned short*)alloc((size_t)L_ * W_ * W_ * 2);
    unsigned short* linwb  = (unsigned short*)alloc((size_t)L_ * W_ * W_ * 2);
    unsigned short* projwb = (unsigned short*)alloc((size_t)W_ * 2 * W_ * 2);
    unsigned short* q1wb   = (unsigned short*)alloc((size_t)128 * W_ * 2);
    int* perm    = (int*)alloc((size_t)E_ * 4);
    int* srcp    = (int*)alloc((size_t)E_ * 4);
    int* count   = (int*)alloc((size_t)BN * 4);
    int* offsets = (int*)alloc((size_t)(BN + 1) * 4);
    int* cursor  = (int*)alloc((size_t)BN * 4);

    // ---- CSR build (edge_index layer-invariant) ----
    hipMemsetAsync(count, 0, (size_t)BN * 4, stream);
    hipMemsetAsync(cursor, 0, (size_t)BN * 4, stream);
    k_hist<<<E_/256, 256, 0, stream>>>(ei, count);
    k_scan<<<1, 256, 0, stream>>>(count, offsets);
    k_place<<<E_/256, 256, 0, stream>>>(ei, offsets, cursor, perm, srcp);

    // ---- weight / U conversions ----
    k_cvt<<<(L_*W_*W_)/1024, 256, 0, stream>>>(w_w, wwb);
    k_cvt<<<(L_*W_*W_)/1024, 256, 0, stream>>>(lin_w, linwb);
    k_cvt<<<(W_*2*W_)/1024, 256, 0, stream>>>(proj_w, projwb);
    k_cvt<<<(128*W_)/1024, 256, 0, stream>>>(q1_w, q1wb);
    k_cvtT<<<dim3(NF_/64, N_/64, B_), 256, 0, stream>>>(U, UT_bf, U_bf);

    k_in_proj<<<BN, 256, 0, stream>>>(x, p_w, p_b, h_bf);

    for (int l = 0; l < L_; ++l) {
        // hT[b][w][n]
        k_T_b2b<<<dim3(W_/64, N_/64, B_), 256, 0, stream>>>(h_bf, hT_bf);
        // spectral fwd split-K: part[b*KS+s][w][f] = sum over n-chunk of hT*UT
        k_mfma_nt<false,0,false><<<dim3(2, 2, B_*KS_), 256, 0, stream>>>(
            hT_bf, N_, (long)W_*N_, N_/KS_,
            UT_bf, N_, (long)NF_*N_, N_/KS_, N_/KS_,
            nullptr, 0, 0, nullptr, 0, 0, 0,
            xft_part, NF_, (long)KS_*65536, 65536,
            nullptr, KS_);
        k_reduce_ks<<<(B_*65536)/256, 256, 0, stream>>>(xft_part, xftT);
        k_fourier_mul<<<W_, 256, 0, stream>>>(four_w + (long)l*W_*W_*NF_, xftT, oftT_bf);
        // xf = U @ oftT^T + h @ w_w^T   (fp32 out, batched over b)
        k_mfma_nt<true,0,false><<<dim3(2, N_/128, B_), 256, 0, stream>>>(
            U_bf, NF_, (long)N_*NF_, 0,
            oftT_bf, NF_, (long)65536, 0, NF_,
            h_bf, W_, (long)N_*W_,
            wwb + (long)l*W_*W_, W_, 0, W_,
            xf, W_, (long)N_*W_, 0,
            nullptr, 1);
        k_gelu_ln<<<BN/4, 256, 0, stream>>>(xf, xf_bf, w_b + l*W_, ln_s + l*W_, ln_b + l*W_);
        // xs = h @ lin_w^T + lin_b  (bf16 out)
        k_mfma_nt<false,1,true><<<dim3(2, BN/128, 1), 256, 0, stream>>>(
            h_bf, W_, 0, 0,
            linwb + (long)l*W_*W_, W_, 0, 0, W_,
            nullptr, 0, 0, nullptr, 0, 0, 0,
            xs_bf, W_, 0, 0,
            lin_b + l*W_, 1);
        k_edge_gate<<<E_/256, 256, 0, stream>>>(perm, srcp, ei, ewt, lif,
            ew_w + l*16, ew_b + l*16, g1_w + l*144, g1_b + l*3,
            g2_w + l*3, g2_b + l, gbuf);
        k_agg_norm<<<BN/4, 256, 0, stream>>>(offsets, srcp, gbuf, xs_bf, xsn_bf);
        // h = xf_bf @ projW1^T + xsn @ projW2^T + proj_b (bf16 out)
        k_mfma_nt<true,1,true><<<dim3(2, BN/128, 1), 256, 0, stream>>>(
            xf_bf, W_, 0, 0,
            projwb, 2*W_, 0, 0, W_,
            xsn_bf, W_, 0,
            projwb + W_, 2*W_, 0, W_,
            h_bf, W_, 0, 0,
            proj_b, 1);
    }
    // q1 = h @ q1_w^T + q1_b (fp32 out into xf)
    k_mfma_nt<false,0,true><<<dim3(1, BN/128, 1), 256, 0, stream>>>(
        h_bf, W_, 0, 0,
        q1wb, W_, 0, 0, W_,
        nullptr, 0, 0, nullptr, 0, 0, 0,
        xf, 128, 0, 0,
        q1_b, 1);
    k_q2<<<BN/4, 256, 0, stream>>>(xf, q2_w, q2_b, (float*)d_out);
}

// Round 4
// 846.611 us; speedup vs baseline: 10.4889x; 1.1021x over previous
//
#include <hip/hip_runtime.h>
#include <hip/hip_bf16.h>

#define B_ 2
#define N_ 16384
#define BN 32768
#define W_ 256
#define NF_ 256
#define E_ 524288
#define L_ 4
#define KS_ 32   // split-K for spectral fwd

typedef __attribute__((ext_vector_type(8))) short bf16x8;
typedef __attribute__((ext_vector_type(4))) float f32x4;

__device__ __forceinline__ unsigned short f2b(float x) {
    __hip_bfloat16 h = __float2bfloat16(x);
    return *reinterpret_cast<unsigned short*>(&h);
}
__device__ __forceinline__ float b2f(unsigned short u) {
    union { unsigned int i; float f; } c; c.i = ((unsigned int)u) << 16; return c.f;
}
__device__ __forceinline__ float geluf(float x) {
    return 0.5f * x * (1.0f + erff(x * 0.70710678118654752440f));
}

// =============== bf16 MFMA NT GEMM: C[m,n] = sum_k A[m,k]B[n,k] (+ optional 2nd product, bias) ===============
// 128x128 tile, 4 waves of 64x64, BK=64, global_load_lds staging with XOR-swizzled LDS.
// z decomposition: zo=z/zdiv, zi=z%zdiv; A1 += zo*A1o+zi*A1i etc. OUTM: 0=f32 store, 1=bf16 store.
template<bool DUAL, int OUTM, bool BIAS>
__global__ __launch_bounds__(256) void k_mfma_nt(
    const unsigned short* __restrict__ A1, int lda1, long A1o, long A1i,
    const unsigned short* __restrict__ B1, int ldb1, long B1o, long B1i, int K1,
    const unsigned short* __restrict__ A2, int lda2, long A2o,
    const unsigned short* __restrict__ B2, int ldb2, long B2o, int K2,
    void* __restrict__ Cv, int ldc, long Co, long Ci,
    const float* __restrict__ bias, int zdiv)
{
    __shared__ unsigned short lds[16384];  // A: [0,8192) ushorts, B: [8192,16384)
    const int t = threadIdx.x;
    const int wid = t >> 6, lane = t & 63;
    const int wr = wid >> 1, wc = wid & 1;
    const int m0 = blockIdx.y * 128, n0 = blockIdx.x * 128;
    const int z = blockIdx.z;
    const int zo = z / zdiv, zi = z - zo * zdiv;
    A1 += zo * A1o + zi * A1i;
    B1 += zo * B1o + zi * B1i;
    if (DUAL) { A2 += zo * A2o; B2 += zo * B2o; }

    const int srow  = t >> 3;                 // staging row 0..31 per pass
    const int sgran = (t & 7) ^ (srow & 7);   // inverse-swizzled source granule
    const int rlo   = lane & 15;
    const int hi    = lane >> 4;

    f32x4 acc[4][4] = {};

    const int nph = DUAL ? 2 : 1;
    for (int ph = 0; ph < nph; ++ph) {
        const unsigned short* A  = (DUAL && ph) ? A2 : A1;
        const unsigned short* Bp = (DUAL && ph) ? B2 : B1;
        const int lda = (DUAL && ph) ? lda2 : lda1;
        const int ldb = (DUAL && ph) ? ldb2 : ldb1;
        const int K   = (DUAL && ph) ? K2 : K1;
        for (int k0 = 0; k0 < K; k0 += 64) {
            __syncthreads();
            #pragma unroll
            for (int j = 0; j < 4; ++j) {
                const unsigned short* ga = A + (long)(m0 + j*32 + srow) * lda + k0 + sgran*8;
                __builtin_amdgcn_global_load_lds(
                    (const __attribute__((address_space(1))) void*)ga,
                    (__attribute__((address_space(3))) void*)&lds[(j*4 + wid) * 512],
                    16, 0, 0);
            }
            #pragma unroll
            for (int j = 0; j < 4; ++j) {
                const unsigned short* gb = Bp + (long)(n0 + j*32 + srow) * ldb + k0 + sgran*8;
                __builtin_amdgcn_global_load_lds(
                    (const __attribute__((address_space(1))) void*)gb,
                    (__attribute__((address_space(3))) void*)&lds[8192 + (j*4 + wid) * 512],
                    16, 0, 0);
            }
            __syncthreads();
            #pragma unroll
            for (int kk = 0; kk < 2; ++kk) {
                const int g8 = (((kk*4 + hi) ^ (lane & 7)) << 3);
                bf16x8 a[4], b[4];
                #pragma unroll
                for (int fm = 0; fm < 4; ++fm)
                    a[fm] = *(const bf16x8*)&lds[(wr*64 + fm*16 + rlo)*64 + g8];
                #pragma unroll
                for (int fn = 0; fn < 4; ++fn)
                    b[fn] = *(const bf16x8*)&lds[8192 + (wc*64 + fn*16 + rlo)*64 + g8];
                #pragma unroll
                for (int fm = 0; fm < 4; ++fm)
                    #pragma unroll
                    for (int fn = 0; fn < 4; ++fn)
                        acc[fm][fn] = __builtin_amdgcn_mfma_f32_16x16x32_bf16(
                            a[fm], b[fn], acc[fm][fn], 0, 0, 0);
            }
        }
    }

    const int mb = m0 + wr*64, nb = n0 + wc*64;
    if (OUTM == 1) {
        unsigned short* C = (unsigned short*)Cv + zo * Co + zi * Ci;
        #pragma unroll
        for (int fn = 0; fn < 4; ++fn) {
            const int n = nb + fn*16 + rlo;
            const float bv = BIAS ? bias[n] : 0.f;
            #pragma unroll
            for (int fm = 0; fm < 4; ++fm)
                #pragma unroll
                for (int r = 0; r < 4; ++r) {
                    const int m = mb + fm*16 + hi*4 + r;
                    C[(long)m*ldc + n] = f2b(acc[fm][fn][r] + bv);
                }
        }
    } else {
        float* C = (float*)Cv + zo * Co + zi * Ci;
        #pragma unroll
        for (int fn = 0; fn < 4; ++fn) {
            const int n = nb + fn*16 + rlo;
            const float bv = BIAS ? bias[n] : 0.f;
            #pragma unroll
            for (int fm = 0; fm < 4; ++fm)
                #pragma unroll
                for (int r = 0; r < 4; ++r) {
                    const int m = mb + fm*16 + hi*4 + r;
                    C[(long)m*ldc + n] = acc[fm][fn][r] + bv;
                }
        }
    }
}

// =============== conversions / transposes ===============
__global__ __launch_bounds__(256) void k_cvt(const float* __restrict__ s, unsigned short* __restrict__ d) {
    long i = (long)(blockIdx.x * 256 + threadIdx.x) * 4;
    float4 v = *(const float4*)&s[i];
    ushort4 u = {f2b(v.x), f2b(v.y), f2b(v.z), f2b(v.w)};
    *(ushort4*)&d[i] = u;
}

// U fp32 [b][N_][NF_] -> UT bf16 [b][NF_][N_]  AND  U_bf bf16 [b][N_][NF_]
__global__ __launch_bounds__(256) void k_cvtT(
    const float* __restrict__ src, unsigned short* __restrict__ dT, unsigned short* __restrict__ dL)
{
    const int b = blockIdx.z;
    src += (long)b * N_ * NF_; dT += (long)b * N_ * NF_; dL += (long)b * N_ * NF_;
    const int r0 = blockIdx.y * 64, c0 = blockIdx.x * 64;
    __shared__ unsigned short tile[64][72];
    const int t = threadIdx.x, lr = t >> 4, lc4 = (t & 15) * 4;
    #pragma unroll
    for (int p = 0; p < 4; ++p) {
        int r = p*16 + lr;
        float4 v = *(const float4*)&src[(long)(r0+r)*NF_ + c0 + lc4];
        ushort4 u = {f2b(v.x), f2b(v.y), f2b(v.z), f2b(v.w)};
        *(ushort4*)&dL[(long)(r0+r)*NF_ + c0 + lc4] = u;
        tile[r][lc4+0]=u.x; tile[r][lc4+1]=u.y; tile[r][lc4+2]=u.z; tile[r][lc4+3]=u.w;
    }
    __syncthreads();
    #pragma unroll
    for (int p = 0; p < 4; ++p) {
        int c = p*16 + lr;
        ushort4 u = {tile[lc4+0][c], tile[lc4+1][c], tile[lc4+2][c], tile[lc4+3][c]};
        *(ushort4*)&dT[(long)(c0+c)*N_ + r0 + lc4] = u;
    }
}

// h bf16 [b][N_][W_] -> hT bf16 [b][W_][N_]
__global__ __launch_bounds__(256) void k_T_b2b(
    const unsigned short* __restrict__ src, unsigned short* __restrict__ dst)
{
    const int b = blockIdx.z;
    src += (long)b * N_ * W_; dst += (long)b * N_ * W_;
    const int r0 = blockIdx.y * 64, c0 = blockIdx.x * 64;
    __shared__ unsigned short tile[64][72];
    const int t = threadIdx.x, lr = t >> 4, lc4 = (t & 15) * 4;
    #pragma unroll
    for (int p = 0; p < 4; ++p) {
        int r = p*16 + lr;
        ushort4 v = *(const ushort4*)&src[(long)(r0+r)*W_ + c0 + lc4];
        tile[r][lc4+0]=v.x; tile[r][lc4+1]=v.y; tile[r][lc4+2]=v.z; tile[r][lc4+3]=v.w;
    }
    __syncthreads();
    #pragma unroll
    for (int p = 0; p < 4; ++p) {
        int c = p*16 + lr;
        ushort4 u = {tile[lc4+0][c], tile[lc4+1][c], tile[lc4+2][c], tile[lc4+3][c]};
        *(ushort4*)&dst[(long)(c0+c)*N_ + r0 + lc4] = u;
    }
}

// =============== small fused kernels ===============
__global__ __launch_bounds__(256) void k_in_proj(
    const float* __restrict__ x, const float* __restrict__ pw,
    const float* __restrict__ pb, unsigned short* __restrict__ h)
{
    int idx = blockIdx.x * 256 + threadIdx.x;
    int node = idx >> 8, w = idx & 255;
    float x0 = x[node*3+0], x1 = x[node*3+1], x2 = x[node*3+2];
    h[idx] = f2b(fmaf(x0, pw[w*3+0], fmaf(x1, pw[w*3+1], fmaf(x2, pw[w*3+2], pb[w]))));
}

// reduce split-K partials: xftT[b][i][f] = sum_s part[b*KS_+s][i][f]
__global__ __launch_bounds__(256) void k_reduce_ks(
    const float* __restrict__ part, float* __restrict__ outp)
{
    int idx = blockIdx.x * 256 + threadIdx.x;   // 0 .. 2*65536-1
    int b = idx >> 16, rem = idx & 65535;
    const float* p = part + (long)b * KS_ * 65536 + rem;
    float s = 0.f;
    #pragma unroll
    for (int k = 0; k < KS_; ++k) s += p[(long)k * 65536];
    outp[idx] = s;
}

// oftT[b][o][f] = sum_i xftT[b][i][f] * fw[i][o][f], bf16 out
__global__ __launch_bounds__(256) void k_fourier_mul(
    const float* __restrict__ fw, const float* __restrict__ xftT,
    unsigned short* __restrict__ oftT)
{
    const int o = blockIdx.x, f = threadIdx.x;
    const float* fwp = fw + (long)o * NF_ + f;
    float a0 = 0.f, a1 = 0.f;
    #pragma unroll 8
    for (int i = 0; i < W_; ++i) {
        float w = fwp[(long)i * W_ * NF_];
        a0 = fmaf(xftT[i*NF_ + f], w, a0);
        a1 = fmaf(xftT[65536 + i*NF_ + f], w, a1);
    }
    oftT[o*NF_ + f] = f2b(a0);
    oftT[65536 + o*NF_ + f] = f2b(a1);
}

__global__ __launch_bounds__(256) void k_gelu_ln(
    const float* __restrict__ xf, unsigned short* __restrict__ out,
    const float* __restrict__ wb, const float* __restrict__ lns, const float* __restrict__ lnb)
{
    const int node = blockIdx.x * 4 + (threadIdx.x >> 6);
    const int lane = threadIdx.x & 63;
    float4 v = *(const float4*)(xf + (long)node*W_ + lane*4);
    float4 bb = *(const float4*)(wb + lane*4);
    float e0 = geluf(v.x+bb.x), e1 = geluf(v.y+bb.y);
    float e2 = geluf(v.z+bb.z), e3 = geluf(v.w+bb.w);
    float s  = e0+e1+e2+e3;
    float s2 = e0*e0+e1*e1+e2*e2+e3*e3;
    #pragma unroll
    for (int o = 32; o; o >>= 1) { s += __shfl_xor(s, o); s2 += __shfl_xor(s2, o); }
    float mean = s * (1.0f/W_);
    float var  = s2 * (1.0f/W_) - mean*mean;
    float inv = rsqrtf(var + 1e-5f);
    float4 sc = *(const float4*)(lns + lane*4);
    float4 bi = *(const float4*)(lnb + lane*4);
    ushort4 o4;
    o4.x = f2b((e0-mean)*inv*sc.x + bi.x);
    o4.y = f2b((e1-mean)*inv*sc.y + bi.y);
    o4.z = f2b((e2-mean)*inv*sc.z + bi.z);
    o4.w = f2b((e3-mean)*inv*sc.w + bi.w);
    *(ushort4*)(out + (long)node*W_ + lane*4) = o4;
}

// =============== CSR build ===============
__global__ __launch_bounds__(256) void k_hist(const int* __restrict__ ei, int* __restrict__ count) {
    int e = blockIdx.x * 256 + threadIdx.x;
    atomicAdd(&count[ei[E_ + e]], 1);
}
__global__ __launch_bounds__(256) void k_scan(const int* __restrict__ count, int* __restrict__ offsets) {
    __shared__ int sums[256];
    const int t = threadIdx.x;
    const int base = t * 128;
    int s = 0;
    for (int i = 0; i < 128; ++i) s += count[base + i];
    sums[t] = s;
    __syncthreads();
    for (int off = 1; off < 256; off <<= 1) {
        int v = (t >= off) ? sums[t - off] : 0;
        __syncthreads();
        sums[t] += v;
        __syncthreads();
    }
    int run = (t == 0) ? 0 : sums[t - 1];
    for (int i = 0; i < 128; ++i) { offsets[base + i] = run; run += count[base + i]; }
    if (t == 255) offsets[BN] = run;
}
__global__ __launch_bounds__(256) void k_place(
    const int* __restrict__ ei, const float* __restrict__ ewt,
    const int* __restrict__ offsets, int* __restrict__ cursor,
    int* __restrict__ srcp, float* __restrict__ ewt_p)
{
    int e = blockIdx.x * 256 + threadIdx.x;
    int dst = ei[E_ + e];
    int pos = offsets[dst] + atomicAdd(&cursor[dst], 1);
    srcp[pos] = ei[e];
    ewt_p[pos] = ewt[e];
}

// =============== fused edge-gate MLP + CSR aggregation + L2 normalize (wave/node) ===============
__global__ __launch_bounds__(256) void k_gate_agg(
    const int* __restrict__ offsets, const int* __restrict__ srcp,
    const float* __restrict__ ewt_p, const float* __restrict__ lif,
    const float* __restrict__ eww, const float* __restrict__ ewb,
    const float* __restrict__ g1w, const float* __restrict__ g1b,
    const float* __restrict__ g2w, const float* __restrict__ g2b,
    const unsigned short* __restrict__ xs, unsigned short* __restrict__ out)
{
    const int node = blockIdx.x * 4 + (threadIdx.x >> 6);
    const int lane = threadIdx.x & 63;
    const int beg = offsets[node], end = offsets[node + 1];
    float lifd[16];
    #pragma unroll
    for (int j = 0; j < 16; ++j) lifd[j] = lif[node*16 + j];
    float a0=0.f, a1=0.f, a2=0.f, a3=0.f;
    for (int c0 = beg; c0 < end; c0 += 64) {
        const int p = c0 + lane;
        float gate = 0.f; int src = 0;
        if (p < end) {
            src = srcp[p];
            const float wv = ewt_p[p];
            float t0 = g1b[0], t1 = g1b[1], t2 = g1b[2];
            #pragma unroll
            for (int j = 0; j < 16; ++j) {
                const float e0 = fmaf(wv, eww[j], ewb[j]);
                const float l1 = lifd[j];
                const float l2 = lif[src*16 + j];
                t0 = fmaf(g1w[j], e0, t0);
                t0 = fmaf(g1w[16 + j], l1, t0);
                t0 = fmaf(g1w[32 + j], l2, t0);
                t1 = fmaf(g1w[48 + j], e0, t1);
                t1 = fmaf(g1w[64 + j], l1, t1);
                t1 = fmaf(g1w[80 + j], l2, t1);
                t2 = fmaf(g1w[96 + j], e0, t2);
                t2 = fmaf(g1w[112 + j], l1, t2);
                t2 = fmaf(g1w[128 + j], l2, t2);
            }
            float z = g2b[0];
            z = fmaf(g2w[0], fmaxf(t0, 0.f), z);
            z = fmaf(g2w[1], fmaxf(t1, 0.f), z);
            z = fmaf(g2w[2], fmaxf(t2, 0.f), z);
            gate = 1.f / (1.f + __expf(-z));
        }
        const int m = min(64, end - c0);
        for (int j = 0; j < m; ++j) {
            const float gv = __shfl(gate, j);
            const int   s  = __shfl(src, j);
            ushort4 v = *(const ushort4*)&xs[(long)s * W_ + lane * 4];
            a0 = fmaf(b2f(v.x), gv, a0);
            a1 = fmaf(b2f(v.y), gv, a1);
            a2 = fmaf(b2f(v.z), gv, a2);
            a3 = fmaf(b2f(v.w), gv, a3);
        }
    }
    float s = a0*a0 + a1*a1 + a2*a2 + a3*a3;
    #pragma unroll
    for (int o = 32; o; o >>= 1) s += __shfl_xor(s, o);
    float inv = 1.f / fmaxf(sqrtf(s), 1e-12f);
    ushort4 r = {f2b(a0*inv), f2b(a1*inv), f2b(a2*inv), f2b(a3*inv)};
    *(ushort4*)(out + (long)node * W_ + lane * 4) = r;
}

// =============== final q2 ===============
__global__ __launch_bounds__(256) void k_q2(
    const float* __restrict__ q1o, const float* __restrict__ q2w,
    const float* __restrict__ q2b, float* __restrict__ out)
{
    int node = blockIdx.x * 4 + (threadIdx.x >> 6);
    int lane = threadIdx.x & 63;
    float a = fmaxf(q1o[(long)node*128 + lane], 0.f) * q2w[lane]
            + fmaxf(q1o[(long)node*128 + 64 + lane], 0.f) * q2w[64 + lane];
    #pragma unroll
    for (int o = 32; o; o >>= 1) a += __shfl_xor(a, o);
    if (lane == 0) out[node] = a + q2b[0];
}

extern "C" void kernel_launch(void* const* d_in, const int* in_sizes, int n_in,
                              void* d_out, int out_size, void* d_ws, size_t ws_size,
                              hipStream_t stream)
{
    const float* x      = (const float*)d_in[0];
    const float* U      = (const float*)d_in[1];
    const int*   ei     = (const int*)  d_in[2];
    const float* ewt    = (const float*)d_in[3];
    const float* lif    = (const float*)d_in[4];
    const float* p_w    = (const float*)d_in[5];
    const float* p_b    = (const float*)d_in[6];
    const float* four_w = (const float*)d_in[7];
    const float* w_w    = (const float*)d_in[8];
    const float* w_b    = (const float*)d_in[9];
    const float* ln_s   = (const float*)d_in[10];
    const float* ln_b   = (const float*)d_in[11];
    const float* lin_w  = (const float*)d_in[12];
    const float* lin_b  = (const float*)d_in[13];
    const float* ew_w   = (const float*)d_in[14];
    const float* ew_b   = (const float*)d_in[15];
    const float* g1_w   = (const float*)d_in[16];
    const float* g1_b   = (const float*)d_in[17];
    const float* g2_w   = (const float*)d_in[18];
    const float* g2_b   = (const float*)d_in[19];
    const float* proj_w = (const float*)d_in[20];
    const float* proj_b = (const float*)d_in[21];
    const float* q1_w   = (const float*)d_in[22];
    const float* q1_b   = (const float*)d_in[23];
    const float* q2_w   = (const float*)d_in[24];
    const float* q2_b   = (const float*)d_in[25];

    char* wsb = (char*)d_ws;
    size_t off = 0;
    auto alloc = [&](size_t bytes) -> void* {
        void* p = wsb + off; off += (bytes + 255) & ~(size_t)255; return p;
    };
    float* xf        = (float*)alloc((size_t)BN * W_ * 4);        // fp32 GEMM out; reused as q1o
    float* xft_part  = (float*)alloc((size_t)B_ * KS_ * 65536 * 4);
    float* xftT      = (float*)alloc((size_t)B_ * 65536 * 4);
    unsigned short* h_bf   = (unsigned short*)alloc((size_t)BN * W_ * 2);
    unsigned short* hT_bf  = (unsigned short*)alloc((size_t)BN * W_ * 2);
    unsigned short* U_bf   = (unsigned short*)alloc((size_t)BN * NF_ * 2);
    unsigned short* UT_bf  = (unsigned short*)alloc((size_t)BN * NF_ * 2);
    unsigned short* xf_bf  = (unsigned short*)alloc((size_t)BN * W_ * 2);
    unsigned short* xs_bf  = (unsigned short*)alloc((size_t)BN * W_ * 2);
    unsigned short* xsn_bf = (unsigned short*)alloc((size_t)BN * W_ * 2);
    unsigned short* oftT_bf= (unsigned short*)alloc((size_t)B_ * 65536 * 2);
    unsigned short* wwb    = (unsigned short*)alloc((size_t)L_ * W_ * W_ * 2);
    unsigned short* linwb  = (unsigned short*)alloc((size_t)L_ * W_ * W_ * 2);
    unsigned short* projwb = (unsigned short*)alloc((size_t)W_ * 2 * W_ * 2);
    unsigned short* q1wb   = (unsigned short*)alloc((size_t)128 * W_ * 2);
    int*   srcp    = (int*)alloc((size_t)E_ * 4);
    float* ewt_p   = (float*)alloc((size_t)E_ * 4);
    int*   count   = (int*)alloc((size_t)BN * 4);   // count+cursor adjacent: one memset
    int*   cursor  = (int*)alloc((size_t)BN * 4);
    int*   offsets = (int*)alloc((size_t)(BN + 1) * 4);

    // ---- CSR build (edge_index layer-invariant) ----
    hipMemsetAsync(count, 0, (size_t)2 * BN * 4, stream);
    k_hist<<<E_/256, 256, 0, stream>>>(ei, count);
    k_scan<<<1, 256, 0, stream>>>(count, offsets);
    k_place<<<E_/256, 256, 0, stream>>>(ei, ewt, offsets, cursor, srcp, ewt_p);

    // ---- weight / U conversions ----
    k_cvt<<<(L_*W_*W_)/1024, 256, 0, stream>>>(w_w, wwb);
    k_cvt<<<(L_*W_*W_)/1024, 256, 0, stream>>>(lin_w, linwb);
    k_cvt<<<(W_*2*W_)/1024, 256, 0, stream>>>(proj_w, projwb);
    k_cvt<<<(128*W_)/1024, 256, 0, stream>>>(q1_w, q1wb);
    k_cvtT<<<dim3(NF_/64, N_/64, B_), 256, 0, stream>>>(U, UT_bf, U_bf);

    k_in_proj<<<BN, 256, 0, stream>>>(x, p_w, p_b, h_bf);

    for (int l = 0; l < L_; ++l) {
        // hT[b][w][n]
        k_T_b2b<<<dim3(W_/64, N_/64, B_), 256, 0, stream>>>(h_bf, hT_bf);
        // spectral fwd split-K: part[b*KS+s][w][f] = sum over n-chunk of hT*UT
        k_mfma_nt<false,0,false><<<dim3(2, 2, B_*KS_), 256, 0, stream>>>(
            hT_bf, N_, (long)W_*N_, N_/KS_,
            UT_bf, N_, (long)NF_*N_, N_/KS_, N_/KS_,
            nullptr, 0, 0, nullptr, 0, 0, 0,
            xft_part, NF_, (long)KS_*65536, 65536,
            nullptr, KS_);
        k_reduce_ks<<<(B_*65536)/256, 256, 0, stream>>>(xft_part, xftT);
        k_fourier_mul<<<W_, 256, 0, stream>>>(four_w + (long)l*W_*W_*NF_, xftT, oftT_bf);
        // xf = U @ oftT^T + h @ w_w^T   (fp32 out, batched over b)
        k_mfma_nt<true,0,false><<<dim3(2, N_/128, B_), 256, 0, stream>>>(
            U_bf, NF_, (long)N_*NF_, 0,
            oftT_bf, NF_, (long)65536, 0, NF_,
            h_bf, W_, (long)N_*W_,
            wwb + (long)l*W_*W_, W_, 0, W_,
            xf, W_, (long)N_*W_, 0,
            nullptr, 1);
        k_gelu_ln<<<BN/4, 256, 0, stream>>>(xf, xf_bf, w_b + l*W_, ln_s + l*W_, ln_b + l*W_);
        // xs = h @ lin_w^T + lin_b  (bf16 out)
        k_mfma_nt<false,1,true><<<dim3(2, BN/128, 1), 256, 0, stream>>>(
            h_bf, W_, 0, 0,
            linwb + (long)l*W_*W_, W_, 0, 0, W_,
            nullptr, 0, 0, nullptr, 0, 0, 0,
            xs_bf, W_, 0, 0,
            lin_b + l*W_, 1);
        // fused gate MLP + CSR aggregation + L2 norm
        k_gate_agg<<<BN/4, 256, 0, stream>>>(offsets, srcp, ewt_p, lif,
            ew_w + l*16, ew_b + l*16, g1_w + l*144, g1_b + l*3,
            g2_w + l*3, g2_b + l, xs_bf, xsn_bf);
        // h = xf_bf @ projW1^T + xsn @ projW2^T + proj_b (bf16 out)
        k_mfma_nt<true,1,true><<<dim3(2, BN/128, 1), 256, 0, stream>>>(
            xf_bf, W_, 0, 0,
            projwb, 2*W_, 0, 0, W_,
            xsn_bf, W_, 0,
            projwb + W_, 2*W_, 0, W_,
            h_bf, W_, 0, 0,
            proj_b, 1);
    }
    // q1 = h @ q1_w^T + q1_b (fp32 out into xf)
    k_mfma_nt<false,0,true><<<dim3(1, BN/128, 1), 256, 0, stream>>>(
        h_bf, W_, 0, 0,
        q1wb, W_, 0, 0, W_,
        nullptr, 0, 0, nullptr, 0, 0, 0,
        xf, 128, 0, 0,
        q1_b, 1);
    k_q2<<<BN/4, 256, 0, stream>>>(xf, q2_w, q2_b, (float*)d_out);
}